// Round 1
// 71.757 us; speedup vs baseline: 1.0200x; 1.0200x over previous
//
#include <hip/hip_runtime.h>

// out[b,u] = prod_i ( x[b,i]*w[i,u] + (1 - w[i,u]) ) = prod_i ( 1 + w[i,u]*(x[b,i]-1) )
// B=2048, IN_DIM=256, UNITS=512
//
// Round 7: pipelined staging.
//  - y = x-1 staged ONCE (transposed [256][32], 32 KB) -> inner op is
//    pk_fma(w, y, 1.0) * acc; the 4 pk_sub/i for (1-w) are gone.
//  - w double-buffered (2 x 16 KB) via global_load_lds width=16 issued one
//    chunk AHEAD of compute: staging never transits VGPRs, global latency
//    hides under ~1100 cyc of chunk compute, ONE barrier per chunk (was 2).
//  - slice-parity bank swizzle kept by pre-swizzling the per-lane GLOBAL
//    source column (col ^ xr) while the LDS dest stays linear (global_load_lds
//    writes wave-uniform base + lane*16).
// Grid (8,64)=512 blocks = 2/CU = 8 waves/CU. LDS 64 KB -> 2 blocks/CU.
// Combine tree + store unchanged from round 6.

typedef float v2f __attribute__((ext_vector_type(2)));

#define B_DIM   2048
#define IN_DIM  256
#define UNITS   512
#define BT      32      // block tile b
#define UT      64      // block tile u
#define BLOCK   256
#define NSL     8       // i-slices per block
#define KIS     32      // i per slice
#define CHUNK   8       // i per slice per w chunk
#define NCH     4       // chunks (KIS/CHUNK)
#define PSTR    68      // combine plane: per-thread float stride (4-way max)
#define PLANE   (32*PSTR)

#define XS_F    (IN_DIM*32)   // 8192 floats: y = x-1, [i][b]
#define WBUF_F  (64*64)       // 4096 floats per w chunk buffer

__global__ __launch_bounds__(BLOCK) void prodw_kernel(
    const float* __restrict__ x,   // [B, IN_DIM]
    const float* __restrict__ w,   // [IN_DIM, UNITS]
    float* __restrict__ out)       // [B, UNITS]
{
    // 64 KB union: [ xs 32K | ws0 16K | ws1 16K ]; combine reuses first 34.8K
    __shared__ __align__(16) float lds[XS_F + 2 * WBUF_F];
    float* __restrict__ xs  = lds;                    // [256][32]
    float* __restrict__ ws0 = lds + XS_F;             // [64][64] chunk buf A
    float* __restrict__ ws1 = lds + XS_F + WBUF_F;    // [64][64] chunk buf B

    const int tid = threadIdx.x;
    const int s   = tid >> 5;        // i-slice 0..7
    const int t   = tid & 31;        // cell-thread 0..31
    const int tb  = t >> 3;          // b-octet 0..3
    const int tu  = t & 7;           // u-octet 0..7
    const int wv  = tid >> 6;        // wave 0..3
    const int ln  = tid & 63;        // lane 0..63
    const int ublk = blockIdx.x * UT;
    const int bblk = blockIdx.y * BT;

    // ---- per-lane prefetch source addresses for w (4 calls/wave/chunk) ----
    // call k covers seg = wv*4+k = 4 LDS rows (1 KB); lane writes 16 B at
    // lds row r = seg*4 + (ln>>4), float cols (ln&15)*4 .. +3.
    // Desired content: wsb[r][c] = w[i(r)][ublk + (c ^ xr(r))],
    // i(r) = (r>>3)*KIS + c*CHUNK + (r&7), xr(r) = ((r>>3)&1)<<2.
    const float* wsrc[4];
    int lofs[4];
#pragma unroll
    for (int k = 0; k < 4; ++k) {
        const int seg = wv * 4 + k;
        const int r   = seg * 4 + (ln >> 4);       // 0..63
        const int ss  = r >> 3;
        const int ii  = r & 7;
        const int xr  = (ss & 1) << 2;
        const int col = ((ln & 15) * 4) ^ xr;
        wsrc[k] = w + (size_t)(ss * KIS + ii) * UNITS + ublk + col;
        lofs[k] = seg * 256;                       // wave-uniform
    }

    // ---- issue w chunk 0 into ws0 (async, drains at first barrier) ----
#pragma unroll
    for (int k = 0; k < 4; ++k)
        __builtin_amdgcn_global_load_lds(
            (const __attribute__((address_space(1))) void*)(wsrc[k]),
            (__attribute__((address_space(3))) void*)(ws0 + lofs[k]), 16, 0, 0);

    // ---- stage ALL of x once, transposed, as y = x-1 ----
    // write bank = b%32 per inst, wave halves 2-way alias -> free
#pragma unroll
    for (int c = 0; c < NCH; ++c) {
#pragma unroll
        for (int r = 0; r < 2; ++r) {
            const int idx  = r * BLOCK + tid;
            const int b    = idx & 31;
            const int srow = idx >> 5;             // 0..15
            const int ss   = srow >> 1;
            const int h    = srow & 1;
            const float4 f = *(const float4*)
                (x + (size_t)(bblk + b) * IN_DIM + ss * KIS + c * CHUNK + h * 4);
            const int row = ss * KIS + c * CHUNK + h * 4;
            xs[(row + 0) * 32 + b] = f.x - 1.0f;
            xs[(row + 1) * 32 + b] = f.y - 1.0f;
            xs[(row + 2) * 32 + b] = f.z - 1.0f;
            xs[(row + 3) * 32 + b] = f.w - 1.0f;
        }
    }

    __align__(16) float af[64];      // acc tile [jb][ju]
    v2f* __restrict__ acc = (v2f*)af;
#pragma unroll
    for (int k = 0; k < 32; ++k) acc[k] = (v2f){1.0f, 1.0f};

    const int swz = (s & 1) << 2;    // compute-side w col swizzle

    __syncthreads();   // x staged (lgkm) + w chunk0 landed (vmcnt drain)

#pragma unroll
    for (int c = 0; c < NCH; ++c) {
        float* const wcur = (c & 1) ? ws1 : ws0;
        float* const wnxt = (c & 1) ? ws0 : ws1;

        // issue next chunk's w loads NOW; they complete by this chunk's barrier
        if (c + 1 < NCH) {
            const size_t coff = (size_t)(c + 1) * CHUNK * UNITS;
#pragma unroll
            for (int k = 0; k < 4; ++k)
                __builtin_amdgcn_global_load_lds(
                    (const __attribute__((address_space(1))) void*)(wsrc[k] + coff),
                    (__attribute__((address_space(3))) void*)(wnxt + lofs[k]),
                    16, 0, 0);
        }

        // ---- compute this chunk's 8 i for slice s ----
#pragma unroll
        for (int ii = 0; ii < CHUNK; ++ii) {
            const int xrow = s * KIS + c * CHUNK + ii;   // global i
            const int wrow = s * CHUNK + ii;             // row in chunk buf
            const float4 ya = *(const float4*)&xs[xrow * 32 + tb * 8];
            const float4 yb = *(const float4*)&xs[xrow * 32 + tb * 8 + 4];
            const float4 w0 = *(const float4*)&wcur[wrow * 64 + ((tu * 8) ^ swz)];
            const float4 w1 = *(const float4*)&wcur[wrow * 64 + ((tu * 8 + 4) ^ swz)];

            v2f wvv[4] = {{w0.x, w0.y}, {w0.z, w0.w}, {w1.x, w1.y}, {w1.z, w1.w}};
            const float yv[8] = {ya.x, ya.y, ya.z, ya.w, yb.x, yb.y, yb.z, yb.w};

#pragma unroll
            for (int jb = 0; jb < 8; ++jb) {
                const v2f yy = {yv[jb], yv[jb]};
#pragma unroll
                for (int q = 0; q < 4; ++q)
                    acc[jb * 4 + q] *= __builtin_elementwise_fma(
                        yy, wvv[q], (v2f){1.0f, 1.0f});
            }
        }
        __syncthreads();   // readers done with wcur; wnxt loads drained here
    }

    // ---- binary-tree combine of 8 slice partials through LDS ----
#pragma unroll
    for (int half = NSL / 2; half >= 1; half >>= 1) {
        __syncthreads();
        if (s >= half && s < 2 * half) {
            float* __restrict__ pl = lds + (size_t)(s - half) * PLANE + t * PSTR;
#pragma unroll
            for (int k = 0; k < 16; ++k)
                *(float4*)&pl[k * 4] = ((const float4*)af)[k];
        }
        __syncthreads();
        if (s < half) {
            const float* __restrict__ pl = lds + (size_t)s * PLANE + t * PSTR;
#pragma unroll
            for (int k = 0; k < 16; ++k) {
                const float4 q = *(const float4*)&pl[k * 4];
                float4* a4 = &((float4*)af)[k];
                a4->x *= q.x; a4->y *= q.y; a4->z *= q.z; a4->w *= q.w;
            }
        }
    }

    // ---- slice 0 stores the 32x64 block tile ----
    if (s == 0) {
#pragma unroll
        for (int jb = 0; jb < 8; ++jb) {
            float* __restrict__ po =
                out + (size_t)(bblk + tb * 8 + jb) * UNITS + ublk + tu * 8;
            *(float4*)(po)     = *(const float4*)&af[jb * 8];
            *(float4*)(po + 4) = *(const float4*)&af[jb * 8 + 4];
        }
    }
}

extern "C" void kernel_launch(void* const* d_in, const int* in_sizes, int n_in,
                              void* d_out, int out_size, void* d_ws, size_t ws_size,
                              hipStream_t stream) {
    const float* x = (const float*)d_in[0];        // 2048*256
    const float* w = (const float*)d_in[1];        // 256*512
    float* out     = (float*)d_out;                // 2048*512

    dim3 grid(UNITS / UT, B_DIM / BT);             // (8, 64) = 512 blocks
    prodw_kernel<<<grid, BLOCK, 0, stream>>>(x, w, out);
}

// Round 2
// 70.513 us; speedup vs baseline: 1.0380x; 1.0176x over previous
//
#include <hip/hip_runtime.h>

// out[b,u] = prod_i ( x[b,i]*w[i,u] + (1 - w[i,u]) ) = prod_i ( 1 + w[i,u]*(x[b,i]-1) )
// B=2048, IN_DIM=256, UNITS=512
//
// Round 8: occupancy push. Round 7's pipelining was worth only 1.4 us ->
// inner loop is latency-exposed at 2 waves/SIMD (grid 2048 waves AND
// VGPR>128 both capped us there). Same total work, split i 16 ways:
// 512-thread blocks (16 slices x 32 cell-threads), each thread 8b x 8u x 16i
// -> 4096 waves = 4 waves/SIMD. __launch_bounds__(512,4) forces VGPR<=128 so
// the doubled occupancy is real. LDS 69.6 KB (combine needs 8 planes) ->
// still 2 blocks/CU. w double-buffer kept (CHUNK=4 -> same 16 KB bufs),
// issued one chunk ahead via global_load_lds w16 with pre-swizzled source.

typedef float v2f __attribute__((ext_vector_type(2)));

#define B_DIM   2048
#define IN_DIM  256
#define UNITS   512
#define BT      32      // block tile b
#define UT      64      // block tile u
#define BLOCK   512
#define NSL     16      // i-slices per block
#define KIS     16      // i per slice
#define CHUNK   4       // i per slice per w chunk
#define NCH     4       // chunks (KIS/CHUNK)
#define PSTR    68      // combine plane: per-thread float stride (4-way max)
#define PLANE   (32*PSTR)

#define XS_F    (IN_DIM*32)   // 8192 floats: y = x-1, [i][b]
#define WBUF_F  (64*64)       // 4096 floats per w chunk buffer (64 rows x 64 u)
#define LDS_F   (8*PLANE)     // 17408 >= XS_F + 2*WBUF_F (16384)

__global__ __launch_bounds__(BLOCK, 4) void prodw_kernel(
    const float* __restrict__ x,   // [B, IN_DIM]
    const float* __restrict__ w,   // [IN_DIM, UNITS]
    float* __restrict__ out)       // [B, UNITS]
{
    __shared__ __align__(16) float lds[LDS_F];
    float* __restrict__ xs  = lds;                    // [256][32]
    float* __restrict__ ws0 = lds + XS_F;             // [64][64] chunk buf A
    float* __restrict__ ws1 = lds + XS_F + WBUF_F;    // [64][64] chunk buf B

    const int tid = threadIdx.x;
    const int s   = tid >> 5;        // i-slice 0..15
    const int t   = tid & 31;        // cell-thread 0..31
    const int tb  = t >> 3;          // b-octet 0..3
    const int tu  = t & 7;           // u-octet 0..7
    const int wv  = tid >> 6;        // wave 0..7
    const int ln  = tid & 63;        // lane 0..63
    const int ublk = blockIdx.x * UT;
    const int bblk = blockIdx.y * BT;

    // ---- per-lane prefetch source addresses for w (2 calls/wave/chunk) ----
    // call k covers seg = wv*2+k (0..15) = 4 LDS rows (1 KB); lane writes 16 B
    // at lds row r = seg*4 + (ln>>4), float cols (ln&15)*4 .. +3.
    // Content: wsb[r][c] = w[i(r)][ublk + (c ^ xr(r))],
    // i(r) = (r>>2)*KIS + c*CHUNK + (r&3), xr(r) = ((r>>2)&1)<<2.
    const float* wsrc[2];
    int lofs[2];
#pragma unroll
    for (int k = 0; k < 2; ++k) {
        const int seg = wv * 2 + k;
        const int r   = seg * 4 + (ln >> 4);       // 0..63
        const int ss  = r >> 2;                    // slice 0..15
        const int ii  = r & 3;
        const int xr  = (ss & 1) << 2;
        const int col = ((ln & 15) * 4) ^ xr;
        wsrc[k] = w + (size_t)(ss * KIS + ii) * UNITS + ublk + col;
        lofs[k] = seg * 256;                       // wave-uniform
    }

    // ---- issue w chunk 0 into ws0 (async, drains at first barrier) ----
#pragma unroll
    for (int k = 0; k < 2; ++k)
        __builtin_amdgcn_global_load_lds(
            (const __attribute__((address_space(1))) void*)(wsrc[k]),
            (__attribute__((address_space(3))) void*)(ws0 + lofs[k]), 16, 0, 0);

    // ---- stage ALL of x once, transposed, as y = x-1 ----
    // write bank = b%32 per inst, wave halves 2-way alias -> free
#pragma unroll
    for (int r = 0; r < 4; ++r) {
        const int idx  = r * BLOCK + tid;          // 0..2047
        const int b    = idx & 31;
        const int srow = idx >> 5;                 // 0..63 (i quad)
        const float4 f = *(const float4*)
            (x + (size_t)(bblk + b) * IN_DIM + srow * 4);
        const int row = srow * 4;
        xs[(row + 0) * 32 + b] = f.x - 1.0f;
        xs[(row + 1) * 32 + b] = f.y - 1.0f;
        xs[(row + 2) * 32 + b] = f.z - 1.0f;
        xs[(row + 3) * 32 + b] = f.w - 1.0f;
    }

    __align__(16) float af[64];      // acc tile [jb][ju]
    v2f* __restrict__ acc = (v2f*)af;
#pragma unroll
    for (int k = 0; k < 32; ++k) acc[k] = (v2f){1.0f, 1.0f};

    const int swz = (s & 1) << 2;    // compute-side w col swizzle

    __syncthreads();   // x staged (lgkm) + w chunk0 landed (vmcnt drain)

#pragma unroll
    for (int c = 0; c < NCH; ++c) {
        float* const wcur = (c & 1) ? ws1 : ws0;
        float* const wnxt = (c & 1) ? ws0 : ws1;

        // issue next chunk's w loads NOW; they complete by this chunk's barrier
        if (c + 1 < NCH) {
            const size_t coff = (size_t)(c + 1) * CHUNK * UNITS;
#pragma unroll
            for (int k = 0; k < 2; ++k)
                __builtin_amdgcn_global_load_lds(
                    (const __attribute__((address_space(1))) void*)(wsrc[k] + coff),
                    (__attribute__((address_space(3))) void*)(wnxt + lofs[k]),
                    16, 0, 0);
        }

        // ---- compute this chunk's 4 i for slice s ----
#pragma unroll
        for (int ii = 0; ii < CHUNK; ++ii) {
            const int xrow = s * KIS + c * CHUNK + ii;   // global i
            const int wrow = s * CHUNK + ii;             // row in chunk buf
            const float4 ya = *(const float4*)&xs[xrow * 32 + tb * 8];
            const float4 yb = *(const float4*)&xs[xrow * 32 + tb * 8 + 4];
            const float4 w0 = *(const float4*)&wcur[wrow * 64 + ((tu * 8) ^ swz)];
            const float4 w1 = *(const float4*)&wcur[wrow * 64 + ((tu * 8 + 4) ^ swz)];

            v2f wvv[4] = {{w0.x, w0.y}, {w0.z, w0.w}, {w1.x, w1.y}, {w1.z, w1.w}};
            const float yv[8] = {ya.x, ya.y, ya.z, ya.w, yb.x, yb.y, yb.z, yb.w};

#pragma unroll
            for (int jb = 0; jb < 8; ++jb) {
                const v2f yy = {yv[jb], yv[jb]};
#pragma unroll
                for (int q = 0; q < 4; ++q)
                    acc[jb * 4 + q] *= __builtin_elementwise_fma(
                        yy, wvv[q], (v2f){1.0f, 1.0f});
            }
        }
        __syncthreads();   // readers done with wcur; wnxt loads drained here
    }

    // ---- binary-tree combine of 16 slice partials through LDS ----
#pragma unroll
    for (int half = NSL / 2; half >= 1; half >>= 1) {
        __syncthreads();
        if (s >= half && s < 2 * half) {
            float* __restrict__ pl = lds + (size_t)(s - half) * PLANE + t * PSTR;
#pragma unroll
            for (int k = 0; k < 16; ++k)
                *(float4*)&pl[k * 4] = ((const float4*)af)[k];
        }
        __syncthreads();
        if (s < half) {
            const float* __restrict__ pl = lds + (size_t)s * PLANE + t * PSTR;
#pragma unroll
            for (int k = 0; k < 16; ++k) {
                const float4 q = *(const float4*)&pl[k * 4];
                float4* a4 = &((float4*)af)[k];
                a4->x *= q.x; a4->y *= q.y; a4->z *= q.z; a4->w *= q.w;
            }
        }
    }

    // ---- slice 0 stores the 32x64 block tile ----
    if (s == 0) {
#pragma unroll
        for (int jb = 0; jb < 8; ++jb) {
            float* __restrict__ po =
                out + (size_t)(bblk + tb * 8 + jb) * UNITS + ublk + tu * 8;
            *(float4*)(po)     = *(const float4*)&af[jb * 8];
            *(float4*)(po + 4) = *(const float4*)&af[jb * 8 + 4];
        }
    }
}

extern "C" void kernel_launch(void* const* d_in, const int* in_sizes, int n_in,
                              void* d_out, int out_size, void* d_ws, size_t ws_size,
                              hipStream_t stream) {
    const float* x = (const float*)d_in[0];        // 2048*256
    const float* w = (const float*)d_in[1];        // 256*512
    float* out     = (float*)d_out;                // 2048*512

    dim3 grid(UNITS / UT, B_DIM / BT);             // (8, 64) = 512 blocks
    prodw_kernel<<<grid, BLOCK, 0, stream>>>(x, w, out);
}